// Round 6
// baseline (45.840 us; speedup 1.0000x reference)
//
#include <hip/hip_runtime.h>

// K-winners-take-all: per row of [4096, 8192] f32, exactly k=410 largest -> 1.0.
// Ties at the k-th value broken by LOWER index (jax.lax.top_k stable semantics).
//
// R6: row in registers (8 x uint4). THREE barriers total (R5 had 6):
//   B0 hist zeroed -> histogram atomics (512 monotone bins over bits>1.5f)
//   B1 hist done   -> EACH WAVE redundantly suffix-scans all 512 bins (8/lane),
//                     shfl-max broadcasts (threshold bin, kkb); candidate total
//                     falls out of the same scan (lane 0) -- no count phase
//   B2 clist done  -> threshold-bin elements collected as (key,index) pairs;
//                     winner inside bin == lexicographic rank (value desc,
//                     index asc) < kkb, computed per-wave from clist.
//                     One code path handles unique k-th AND ties exactly.
// Write: 2 float compares/elem + NT float4 stores.
// Exact fallbacks kept (never taken on N(0,1) data): f2ord block radix + eqmask.

#define E      8192
#define BLK    256
#define KACT   410
#define NBINS  512
#define SHIFTB 15
#define BASEB  0x3FC00000u   // bits of 1.5f
#define CCAP   64

typedef float f32x4 __attribute__((ext_vector_type(4)));

__device__ __forceinline__ unsigned f2ord(unsigned u) {
    return (u & 0x80000000u) ? ~u : (u | 0x80000000u);
}

// fallback-only: rank of equal-element (it,j) of thread t among all equals.
__device__ __noinline__ unsigned eq_rank(const unsigned* eqmask, int t, int it, int j) {
    const unsigned m_lt = (2u << (4 * it + 3)) - 1u;
    const unsigned m_eq = (1u << (4 * it + j)) - 1u;
    const unsigned m_gt = (1u << (4 * it)) - 1u;
    unsigned cnt = 0;
    for (int tp = 0; tp < BLK; ++tp) {
        unsigned em = eqmask[tp];
        unsigned msk = (tp < t) ? m_lt : ((tp == t) ? m_eq : m_gt);
        cnt += __popc(em & msk);
    }
    return cnt;
}

__global__ __launch_bounds__(BLK, 4)
void kwta_kernel(const float* __restrict__ x, float* __restrict__ out) {
    __shared__ unsigned hist[NBINS];     // 2 KB
    __shared__ unsigned clk[CCAP];       // threshold-bin keys
    __shared__ unsigned cli[CCAP];       // threshold-bin indices
    __shared__ unsigned eqmask[BLK];     // fallback only
    __shared__ unsigned wsum[4];         // fallback only
    __shared__ unsigned s_cnum, s_prefix, s_kk;

    const int t    = threadIdx.x;
    const int lane = t & 63;
    const size_t rowbase = (size_t)blockIdx.x * (size_t)E;
    const uint4* xin = reinterpret_cast<const uint4*>(x + rowbase);

    // issue row loads first; they fly while we zero the histogram
    uint4 kv[8];
    #pragma unroll
    for (int it = 0; it < 8; ++it) kv[it] = xin[it * BLK + t];

    for (int i = t; i < NBINS; i += BLK) hist[i] = 0u;
    if (t == 0) { s_cnum = 0u; s_prefix = 0u; s_kk = KACT; }
    __syncthreads();                                            // B0

    // ---- histogram candidates (> 1.5) from registers ----
    #pragma unroll
    for (int it = 0; it < 8; ++it) {
        uint4 v = kv[it];
        unsigned a[4] = {v.x, v.y, v.z, v.w};
        #pragma unroll
        for (int j = 0; j < 4; ++j) {
            if (__uint_as_float(a[j]) > 1.5f) {
                unsigned bb = (a[j] - BASEB) >> SHIFTB;
                bb = (bb > NBINS - 1u) ? (NBINS - 1u) : bb;
                atomicAdd(&hist[bb], 1u);
            }
        }
    }
    __syncthreads();                                            // B1

    // ---- per-wave full suffix-scan of all 512 bins (redundant per wave) ----
    unsigned h[8]; unsigned local = 0;
    #pragma unroll
    for (int j2 = 0; j2 < 8; ++j2) { h[j2] = hist[8 * lane + j2]; local += h[j2]; }
    unsigned run = local;
    #pragma unroll
    for (int d = 1; d < 64; d <<= 1) {
        unsigned o = __shfl_down(run, d);
        run += (lane + d < 64) ? o : 0u;
    }
    const unsigned total = __shfl(run, 0);     // all candidates (> 1.5)
    const unsigned tail  = run - local;        // suffix over higher lanes
    unsigned bsel = 0, kkb = 0;
    {
        unsigned suf = tail;
        #pragma unroll
        for (int j2 = 7; j2 >= 0; --j2) {      // suf = count in bins > (8*lane+j2)
            if (suf < KACT && suf + h[j2] >= KACT) { bsel = 8u * lane + j2; kkb = KACT - suf; }
            suf += h[j2];
        }
    }
    unsigned packed = kkb ? ((bsel << 16) | kkb) : 0u;   // exactly one lane nonzero
    #pragma unroll
    for (int d = 1; d < 64; d <<= 1) {
        unsigned o = __shfl_xor(packed, d);
        packed = (o > packed) ? o : packed;
    }
    bsel = packed >> 16; kkb = packed & 0xFFFFu;

    bool fb = (total < KACT);   // threshold could be <= 1.5 -> exact fallback

    const unsigned binlo = BASEB + (bsel << SHIFTB);
    const float binlo_f = __uint_as_float(binlo);
    const float binhi_f = (bsel == NBINS - 1u) ? __uint_as_float(0x7F800000u)  // +inf
                                               : __uint_as_float(binlo + (1u << SHIFTB));

    // ---- collect threshold-bin (key, index) pairs ----
    if (!fb) {
        #pragma unroll
        for (int it = 0; it < 8; ++it) {
            uint4 v = kv[it];
            unsigned a[4] = {v.x, v.y, v.z, v.w};
            #pragma unroll
            for (int j = 0; j < 4; ++j) {
                float xf = __uint_as_float(a[j]);
                if (xf >= binlo_f && xf < binhi_f && xf > 1.5f) {
                    unsigned p = atomicAdd(&s_cnum, 1u);
                    if (p < CCAP) { clk[p] = a[j]; cli[p] = (unsigned)(it * 1024 + t * 4 + j); }
                }
            }
        }
    }
    __syncthreads();                                            // B2
    const unsigned cn = s_cnum;
    if (cn > CCAP) fb = true;   // adversarial pile-up -> exact fallback

    if (!fb) {
        // ---- fast path: winners = (x >= binhi) | (in-bin lex-rank < kkb) ----
        f32x4* o = reinterpret_cast<f32x4*>(out + rowbase);
        #pragma unroll
        for (int it = 0; it < 8; ++it) {
            uint4 v = kv[it];
            unsigned a[4] = {v.x, v.y, v.z, v.w};
            float rs[4];
            #pragma unroll
            for (int j = 0; j < 4; ++j) {
                unsigned key = a[j];
                float xf = __uint_as_float(key);
                float val;
                if (xf >= binhi_f) val = 1.0f;
                else if (xf >= binlo_f) {
                    // in threshold bin (rare: ~4-8 elements/row total)
                    unsigned idx = (unsigned)(it * 1024 + t * 4 + j);
                    unsigned rank = 0;
                    for (unsigned q = 0; q < cn; ++q) {
                        unsigned kq = clk[q];
                        rank += (kq > key || (kq == key && cli[q] < idx)) ? 1u : 0u;
                    }
                    val = (rank < kkb) ? 1.0f : 0.0f;
                } else val = 0.0f;
                rs[j] = val;
            }
            f32x4 rr; rr.x = rs[0]; rr.y = rs[1]; rr.z = rs[2]; rr.w = rs[3];
            __builtin_nontemporal_store(rr, o + it * BLK + t);
        }
        return;
    }

    // ---- exact fallback (never on this data): 4x8-bit f2ord radix + eqmask ----
    #pragma unroll 1
    for (int p = 0; p < 4; ++p) {
        const int shift = 24 - 8 * p;
        const unsigned fixedmask = (p == 0) ? 0u : (0xFFFFFFFFu << (shift + 8));
        hist[t] = 0u;
        __syncthreads();
        const unsigned pref = s_prefix;
        #pragma unroll
        for (int it = 0; it < 8; ++it) {
            uint4 v = kv[it];
            unsigned a[4] = {v.x, v.y, v.z, v.w};
            #pragma unroll
            for (int j = 0; j < 4; ++j) {
                unsigned key = f2ord(a[j]);
                if ((key & fixedmask) == pref)
                    atomicAdd(&hist[(key >> shift) & 255u], 1u);
            }
        }
        __syncthreads();
        if (t < 64) {
            const int b4 = t * 4;
            unsigned h0 = hist[b4], h1 = hist[b4 + 1], h2 = hist[b4 + 2], h3 = hist[b4 + 3];
            unsigned local2 = h0 + h1 + h2 + h3;
            unsigned run2 = local2;
            #pragma unroll
            for (int d = 1; d < 64; d <<= 1) {
                unsigned o = __shfl_down(run2, d);
                run2 += (lane + d < 64) ? o : 0u;
            }
            const unsigned tail2 = run2 - local2;
            const unsigned kk = s_kk;
            const unsigned s3 = tail2 + h3;
            const unsigned s2 = s3 + h2;
            const unsigned s1 = s2 + h1;
            const unsigned s0 = s1 + h0;
            if      (s0 >= kk && s1    < kk) { s_prefix = pref | ((unsigned)(b4 + 0) << shift); s_kk = kk - s1; }
            else if (s1 >= kk && s2    < kk) { s_prefix = pref | ((unsigned)(b4 + 1) << shift); s_kk = kk - s2; }
            else if (s2 >= kk && s3    < kk) { s_prefix = pref | ((unsigned)(b4 + 2) << shift); s_kk = kk - s3; }
            else if (s3 >= kk && tail2 < kk) { s_prefix = pref | ((unsigned)(b4 + 3) << shift); s_kk = kk - tail2; }
        }
        __syncthreads();
    }
    const unsigned T = s_prefix, kkT = s_kk;

    unsigned myeq = 0u;
    #pragma unroll
    for (int it = 0; it < 8; ++it) {
        uint4 v = kv[it];
        unsigned a[4] = {v.x, v.y, v.z, v.w};
        #pragma unroll
        for (int j = 0; j < 4; ++j)
            myeq |= (f2ord(a[j]) == T ? 1u : 0u) << (it * 4 + j);
    }
    eqmask[t] = myeq;
    unsigned pm = __popc(myeq);
    #pragma unroll
    for (int d = 1; d < 64; d <<= 1) pm += __shfl_down(pm, d);
    if (lane == 0) wsum[t >> 6] = pm;
    __syncthreads();
    const unsigned m = wsum[0] + wsum[1] + wsum[2] + wsum[3];
    const bool allwin = (kkT == m);

    f32x4* o = reinterpret_cast<f32x4*>(out + rowbase);
    #pragma unroll
    for (int it = 0; it < 8; ++it) {
        uint4 v = kv[it];
        unsigned a[4] = {v.x, v.y, v.z, v.w};
        float rs[4];
        #pragma unroll
        for (int j = 0; j < 4; ++j) {
            unsigned key = f2ord(a[j]);
            float val;
            if (key > T)       val = 1.0f;
            else if (key != T) val = 0.0f;
            else if (allwin)   val = 1.0f;
            else               val = (eq_rank(eqmask, t, it, j) < kkT) ? 1.0f : 0.0f;
            rs[j] = val;
        }
        f32x4 rr; rr.x = rs[0]; rr.y = rs[1]; rr.z = rs[2]; rr.w = rs[3];
        __builtin_nontemporal_store(rr, o + it * BLK + t);
    }
}

extern "C" void kernel_launch(void* const* d_in, const int* in_sizes, int n_in,
                              void* d_out, int out_size, void* d_ws, size_t ws_size,
                              hipStream_t stream) {
    const float* x = (const float*)d_in[0];
    float* out = (float*)d_out;
    const int rows = in_sizes[0] / E;   // 4096
    kwta_kernel<<<dim3(rows), dim3(BLK), 0, stream>>>(x, out);
}

// Round 7
// 44.440 us; speedup vs baseline: 1.0315x; 1.0315x over previous
//
#include <hip/hip_runtime.h>

// K-winners-take-all: per row of [4096, 8192] f32, exactly k=410 largest -> 1.0.
// Ties at the k-th value broken by LOWER index (jax.lax.top_k stable semantics).
//
// R7: 512 threads/block, 16 elems/thread (kv[4] x uint4) -> half the per-thread
// register state of R6. launch_bounds(512,8) = 8 waves/EU = 4 blocks/CU = 100%
// occupancy (R6 measured 54% under (256,4); that cap was the limiter: VALU 19%,
// conflicts trivial, BW 70% of achievable). R3 lesson: never clamp VGPR below
// the row footprint -- here the footprint is halved instead.
// Selection structure unchanged from R6 (3 barriers):
//   B0 hist zeroed -> 512-bin monotone histogram of bits>1.5f
//   B1 hist done   -> per-wave redundant suffix-scan, shfl-max broadcast
//   B2 clist done  -> (key,index) pairs in threshold bin; winner = lex-rank < kkb
// Exact fallbacks kept: f2ord block radix + eqmask (never taken on N(0,1)).

#define E      8192
#define BLK    512
#define PER    4            // uint4 per thread
#define KACT   410
#define NBINS  512
#define SHIFTB 15
#define BASEB  0x3FC00000u  // bits of 1.5f
#define CCAP   64

typedef float f32x4 __attribute__((ext_vector_type(4)));

__device__ __forceinline__ unsigned f2ord(unsigned u) {
    return (u & 0x80000000u) ? ~u : (u | 0x80000000u);
}

// fallback-only: rank of equal-element (it,j) of thread t among all equals.
// element index e = (it*BLK + t)*4 + j ; eqmask[t'] bit (it'*4+j') marks equals.
__device__ __noinline__ unsigned eq_rank(const unsigned* eqmask, int t, int it, int j) {
    const unsigned m_lt = (2u << (4 * it + 3)) - 1u;   // groups <= it fully
    const unsigned m_eq = (1u << (4 * it + j)) - 1u;   // own bits below (it,j)
    const unsigned m_gt = (1u << (4 * it)) - 1u;       // groups < it only
    unsigned cnt = 0;
    for (int tp = 0; tp < BLK; ++tp) {
        unsigned em = eqmask[tp];
        unsigned msk = (tp < t) ? m_lt : ((tp == t) ? m_eq : m_gt);
        cnt += __popc(em & msk);
    }
    return cnt;
}

__global__ __launch_bounds__(BLK, 8)
void kwta_kernel(const float* __restrict__ x, float* __restrict__ out) {
    __shared__ unsigned hist[NBINS];     // 2 KB
    __shared__ unsigned clk[CCAP];       // threshold-bin keys
    __shared__ unsigned cli[CCAP];       // threshold-bin indices
    __shared__ unsigned eqmask[BLK];     // fallback only (2 KB)
    __shared__ unsigned wsum[8];         // fallback only
    __shared__ unsigned s_cnum, s_prefix, s_kk;

    const int t    = threadIdx.x;
    const int lane = t & 63;
    const size_t rowbase = (size_t)blockIdx.x * (size_t)E;
    const uint4* xin = reinterpret_cast<const uint4*>(x + rowbase);

    // issue row loads first; they fly while we zero the histogram
    uint4 kv[PER];
    #pragma unroll
    for (int it = 0; it < PER; ++it) kv[it] = xin[it * BLK + t];

    if (t < NBINS) hist[t] = 0u;
    if (t == 0) { s_cnum = 0u; s_prefix = 0u; s_kk = KACT; }
    __syncthreads();                                            // B0

    // ---- histogram candidates (> 1.5) from registers ----
    #pragma unroll
    for (int it = 0; it < PER; ++it) {
        uint4 v = kv[it];
        unsigned a[4] = {v.x, v.y, v.z, v.w};
        #pragma unroll
        for (int j = 0; j < 4; ++j) {
            if (__uint_as_float(a[j]) > 1.5f) {
                unsigned bb = (a[j] - BASEB) >> SHIFTB;
                bb = (bb > NBINS - 1u) ? (NBINS - 1u) : bb;
                atomicAdd(&hist[bb], 1u);
            }
        }
    }
    __syncthreads();                                            // B1

    // ---- per-wave full suffix-scan of all 512 bins (redundant per wave) ----
    unsigned h[8]; unsigned local = 0;
    #pragma unroll
    for (int j2 = 0; j2 < 8; ++j2) { h[j2] = hist[8 * lane + j2]; local += h[j2]; }
    unsigned run = local;
    #pragma unroll
    for (int d = 1; d < 64; d <<= 1) {
        unsigned o = __shfl_down(run, d);
        run += (lane + d < 64) ? o : 0u;
    }
    const unsigned total = __shfl(run, 0);     // all candidates (> 1.5)
    const unsigned tail  = run - local;        // suffix over higher lanes
    unsigned bsel = 0, kkb = 0;
    {
        unsigned suf = tail;
        #pragma unroll
        for (int j2 = 7; j2 >= 0; --j2) {      // suf = count in bins > (8*lane+j2)
            if (suf < KACT && suf + h[j2] >= KACT) { bsel = 8u * lane + j2; kkb = KACT - suf; }
            suf += h[j2];
        }
    }
    unsigned packed = kkb ? ((bsel << 16) | kkb) : 0u;   // exactly one lane nonzero
    #pragma unroll
    for (int d = 1; d < 64; d <<= 1) {
        unsigned o = __shfl_xor(packed, d);
        packed = (o > packed) ? o : packed;
    }
    bsel = packed >> 16; kkb = packed & 0xFFFFu;

    bool fb = (total < KACT);   // threshold could be <= 1.5 -> exact fallback

    const unsigned binlo = BASEB + (bsel << SHIFTB);
    const float binlo_f = __uint_as_float(binlo);
    const float binhi_f = (bsel == NBINS - 1u) ? __uint_as_float(0x7F800000u)  // +inf
                                               : __uint_as_float(binlo + (1u << SHIFTB));

    // ---- collect threshold-bin (key, index) pairs ----
    if (!fb) {
        #pragma unroll
        for (int it = 0; it < PER; ++it) {
            uint4 v = kv[it];
            unsigned a[4] = {v.x, v.y, v.z, v.w};
            #pragma unroll
            for (int j = 0; j < 4; ++j) {
                float xf = __uint_as_float(a[j]);
                if (xf >= binlo_f && xf < binhi_f && xf > 1.5f) {
                    unsigned p = atomicAdd(&s_cnum, 1u);
                    if (p < CCAP) { clk[p] = a[j]; cli[p] = (unsigned)((it * BLK + t) * 4 + j); }
                }
            }
        }
    }
    __syncthreads();                                            // B2
    const unsigned cn = s_cnum;
    if (cn > CCAP) fb = true;   // adversarial pile-up -> exact fallback

    if (!fb) {
        // ---- fast path: winners = (x >= binhi) | (in-bin lex-rank < kkb) ----
        f32x4* o = reinterpret_cast<f32x4*>(out + rowbase);
        #pragma unroll
        for (int it = 0; it < PER; ++it) {
            uint4 v = kv[it];
            unsigned a[4] = {v.x, v.y, v.z, v.w};
            float rs[4];
            #pragma unroll
            for (int j = 0; j < 4; ++j) {
                unsigned key = a[j];
                float xf = __uint_as_float(key);
                float val;
                if (xf >= binhi_f) val = 1.0f;
                else if (xf >= binlo_f) {
                    // in threshold bin (rare: ~4-8 elements/row total)
                    unsigned idx = (unsigned)((it * BLK + t) * 4 + j);
                    unsigned rank = 0;
                    for (unsigned q = 0; q < cn; ++q) {
                        unsigned kq = clk[q];
                        rank += (kq > key || (kq == key && cli[q] < idx)) ? 1u : 0u;
                    }
                    val = (rank < kkb) ? 1.0f : 0.0f;
                } else val = 0.0f;
                rs[j] = val;
            }
            f32x4 rr; rr.x = rs[0]; rr.y = rs[1]; rr.z = rs[2]; rr.w = rs[3];
            __builtin_nontemporal_store(rr, o + it * BLK + t);
        }
        return;
    }

    // ---- exact fallback (never on this data): 4x8-bit f2ord radix + eqmask ----
    #pragma unroll 1
    for (int p = 0; p < 4; ++p) {
        const int shift = 24 - 8 * p;
        const unsigned fixedmask = (p == 0) ? 0u : (0xFFFFFFFFu << (shift + 8));
        if (t < 256) hist[t] = 0u;
        __syncthreads();
        const unsigned pref = s_prefix;
        #pragma unroll
        for (int it = 0; it < PER; ++it) {
            uint4 v = kv[it];
            unsigned a[4] = {v.x, v.y, v.z, v.w};
            #pragma unroll
            for (int j = 0; j < 4; ++j) {
                unsigned key = f2ord(a[j]);
                if ((key & fixedmask) == pref)
                    atomicAdd(&hist[(key >> shift) & 255u], 1u);
            }
        }
        __syncthreads();
        if (t < 64) {
            const int b4 = t * 4;
            unsigned h0 = hist[b4], h1 = hist[b4 + 1], h2 = hist[b4 + 2], h3 = hist[b4 + 3];
            unsigned local2 = h0 + h1 + h2 + h3;
            unsigned run2 = local2;
            #pragma unroll
            for (int d = 1; d < 64; d <<= 1) {
                unsigned o = __shfl_down(run2, d);
                run2 += (lane + d < 64) ? o : 0u;
            }
            const unsigned tail2 = run2 - local2;
            const unsigned kk = s_kk;
            const unsigned s3 = tail2 + h3;
            const unsigned s2 = s3 + h2;
            const unsigned s1 = s2 + h1;
            const unsigned s0 = s1 + h0;
            if      (s0 >= kk && s1    < kk) { s_prefix = pref | ((unsigned)(b4 + 0) << shift); s_kk = kk - s1; }
            else if (s1 >= kk && s2    < kk) { s_prefix = pref | ((unsigned)(b4 + 1) << shift); s_kk = kk - s2; }
            else if (s2 >= kk && s3    < kk) { s_prefix = pref | ((unsigned)(b4 + 2) << shift); s_kk = kk - s3; }
            else if (s3 >= kk && tail2 < kk) { s_prefix = pref | ((unsigned)(b4 + 3) << shift); s_kk = kk - tail2; }
        }
        __syncthreads();
    }
    const unsigned T = s_prefix, kkT = s_kk;

    unsigned myeq = 0u;
    #pragma unroll
    for (int it = 0; it < PER; ++it) {
        uint4 v = kv[it];
        unsigned a[4] = {v.x, v.y, v.z, v.w};
        #pragma unroll
        for (int j = 0; j < 4; ++j)
            myeq |= (f2ord(a[j]) == T ? 1u : 0u) << (it * 4 + j);
    }
    eqmask[t] = myeq;
    unsigned pm = __popc(myeq);
    #pragma unroll
    for (int d = 1; d < 64; d <<= 1) pm += __shfl_down(pm, d);
    if (lane == 0) wsum[t >> 6] = pm;
    __syncthreads();
    unsigned m = 0;
    #pragma unroll
    for (int w = 0; w < 8; ++w) m += wsum[w];
    const bool allwin = (kkT == m);

    f32x4* o = reinterpret_cast<f32x4*>(out + rowbase);
    #pragma unroll
    for (int it = 0; it < PER; ++it) {
        uint4 v = kv[it];
        unsigned a[4] = {v.x, v.y, v.z, v.w};
        float rs[4];
        #pragma unroll
        for (int j = 0; j < 4; ++j) {
            unsigned key = f2ord(a[j]);
            float val;
            if (key > T)       val = 1.0f;
            else if (key != T) val = 0.0f;
            else if (allwin)   val = 1.0f;
            else               val = (eq_rank(eqmask, t, it, j) < kkT) ? 1.0f : 0.0f;
            rs[j] = val;
        }
        f32x4 rr; rr.x = rs[0]; rr.y = rs[1]; rr.z = rs[2]; rr.w = rs[3];
        __builtin_nontemporal_store(rr, o + it * BLK + t);
    }
}

extern "C" void kernel_launch(void* const* d_in, const int* in_sizes, int n_in,
                              void* d_out, int out_size, void* d_ws, size_t ws_size,
                              hipStream_t stream) {
    const float* x = (const float*)d_in[0];
    float* out = (float*)d_out;
    const int rows = in_sizes[0] / E;   // 4096
    kwta_kernel<<<dim3(rows), dim3(BLK), 0, stream>>>(x, out);
}